// Round 5
// baseline (2316.039 us; speedup 1.0000x reference)
//
#include <hip/hip_runtime.h>
#include <hip/hip_bf16.h>

typedef __hip_bfloat16 bf16;

// H is fixed at 64 by the reference architecture; N, E, P come from in_sizes.

// ---------------- dtype forensics (masks / indices) ----------------
// modes: 0=u8/bool, 1=int32, 2=float32, 3=int64, 4=float64
__global__ __launch_bounds__(256) void forensic_kernel(const unsigned int* __restrict__ mask_w,
                                                       const unsigned int* __restrict__ idx_w,
                                                       int nw_mask, int nw_idx,
                                                       int* __restrict__ flags) {
    __shared__ int sm[6];
    int t = threadIdx.x;
    if (t < 6) sm[t] = 0;
    __syncthreads();
    int m_gt1 = 0, m_f32 = 0, m_f64 = 0, m_oddnz = 0, i_hi = 0, i_oddnz = 0;
    for (int i = t; i < nw_mask; i += 256) {
        unsigned int w = mask_w[i];
        if (w > 1u && w != 0x3F800000u && w != 0x3FF00000u) m_gt1++;
        if (w == 0x3F800000u) m_f32++;
        if ((i & 1) && w == 0x3FF00000u) m_f64++;
        if ((i & 1) && w != 0u) m_oddnz++;
    }
    for (int i = t; i < nw_idx; i += 256) {
        unsigned int v = idx_w[i];
        if (v >= 0x20000000u) i_hi++;
        if ((i & 1) && v != 0u) i_oddnz++;
    }
    atomicAdd(&sm[0], m_gt1);
    atomicAdd(&sm[1], m_f32);
    atomicAdd(&sm[2], m_f64);
    atomicAdd(&sm[3], m_oddnz);
    atomicAdd(&sm[4], i_hi);
    atomicAdd(&sm[5], i_oddnz);
    __syncthreads();
    if (t == 0) {
        int mmode;
        if (sm[1] > 50) mmode = 2;
        else if (sm[2] > 50) mmode = 4;
        else if (sm[0] > 50) mmode = 0;
        else if (sm[3] > 50) mmode = 1;
        else mmode = 3;
        int imode;
        if (sm[4] > (nw_idx * 3) / 4) imode = 2;
        else if (sm[4] > nw_idx / 4) imode = 4;
        else if (sm[5] > 50) imode = 1;
        else imode = 3;
        flags[0] = mmode;
        flags[1] = imode;
    }
}

__device__ __forceinline__ int fetch_idx(const void* p, int e, int mode) {
    switch (mode) {
        case 1: return ((const int*)p)[e];
        case 3: return (int)(((const long long*)p)[e]);
        case 2: return (int)(((const float*)p)[e]);
        default: return (int)(((const double*)p)[e]);
    }
}

__global__ __launch_bounds__(256) void conv_mask_kernel(const void* __restrict__ m,
                                                        const int* __restrict__ flags, int n,
                                                        unsigned char* __restrict__ out) {
    int mode = flags[0];
    int i = blockIdx.x * 256 + threadIdx.x;
    if (i >= n) return;
    bool v;
    switch (mode) {
        case 0: v = ((const unsigned char*)m)[i] != 0; break;
        case 1: v = ((const int*)m)[i] != 0; break;
        case 2: v = ((const float*)m)[i] != 0.f; break;
        case 3: v = ((const long long*)m)[i] != 0; break;
        default: v = ((const double*)m)[i] != 0.0; break;
    }
    out[i] = v ? 1 : 0;
}

// ---------------- CSR build ----------------

__global__ __launch_bounds__(256) void hist_kernel(const void* __restrict__ row,
                                                   const int* __restrict__ flags, int e_cnt, int n,
                                                   int* __restrict__ cnt) {
    int imode = flags[1];
    int e = blockIdx.x * 256 + threadIdx.x;
    if (e >= e_cnt) return;
    int r = fetch_idx(row, e, imode);
    if ((unsigned)r < (unsigned)n) atomicAdd(&cnt[r], 1);
}

__global__ __launch_bounds__(1024) void scan_kernel(const int* __restrict__ cnt, int n,
                                                    int* __restrict__ row_ptr,
                                                    int* __restrict__ cursor) {
    __shared__ int sh[1024];
    int t = threadIdx.x;
    int chunk = (n + 1023) / 1024;
    int base = t * chunk;
    int s = 0;
    for (int i = 0; i < chunk; i++) {
        int idx = base + i;
        if (idx < n) s += cnt[idx];
    }
    sh[t] = s;
    __syncthreads();
    for (int off = 1; off < 1024; off <<= 1) {
        int v = (t >= off) ? sh[t - off] : 0;
        __syncthreads();
        sh[t] += v;
        __syncthreads();
    }
    int run = sh[t] - s;  // exclusive prefix
    for (int i = 0; i < chunk; i++) {
        int idx = base + i;
        if (idx < n) {
            int c = cnt[idx];
            row_ptr[idx] = run;
            cursor[idx] = run;
            run += c;
        }
    }
    if (t == 1023) row_ptr[n] = sh[1023];
}

__global__ __launch_bounds__(256) void scatter_kernel(const void* __restrict__ row,
                                                      const void* __restrict__ col,
                                                      const float* __restrict__ vals,
                                                      const int* __restrict__ flags, int e_cnt,
                                                      int n, int* __restrict__ cursor,
                                                      int* __restrict__ col_s,
                                                      float* __restrict__ val_s) {
    int imode = flags[1];
    int e = blockIdx.x * 256 + threadIdx.x;
    if (e >= e_cnt) return;
    int r = fetch_idx(row, e, imode);
    if ((unsigned)r >= (unsigned)n) return;
    int c = fetch_idx(col, e, imode);
    if ((unsigned)c >= (unsigned)n) c = 0;
    int pos = atomicAdd(&cursor[r], 1);
    col_s[pos] = c;
    val_s[pos] = vals[e];
}

// ---------------- dense 64x64 GEMM: Y[n][k] = sum_h X[n][h] * Wg[k*64+h] ----------------
// W transposed into LDS, stride 65 (+1 pad). 4 rows / 256-thread block.

__global__ __launch_bounds__(256) void gemm64(const float* __restrict__ X,
                                              const float* __restrict__ Wg,
                                              float* __restrict__ Y,
                                              const unsigned char* __restrict__ mask, int n) {
    __shared__ float Ws[64 * 65];
    __shared__ float Xs[4][64];
    int t = threadIdx.x;
#pragma unroll
    for (int i = 0; i < 16; i++) {
        int idx = t + i * 256;
        int k = idx >> 6, hh = idx & 63;
        Ws[hh * 65 + k] = Wg[idx];
    }
    int r = t >> 6, lane = t & 63;
    int rowi = blockIdx.x * 4 + r;
    float xv = 0.f;
    if (rowi < n) {
        xv = X[(size_t)rowi * 64 + lane];
        if (mask != nullptr && mask[rowi]) xv = 0.f;
    }
    Xs[r][lane] = xv;
    __syncthreads();
    float acc = 0.f;
#pragma unroll
    for (int hh = 0; hh < 64; hh++) acc = fmaf(Xs[r][hh], Ws[hh * 65 + lane], acc);
    if (rowi < n) Y[(size_t)rowi * 64 + lane] = acc;
}

// ---------------- CSR SpMM + bias + PReLU: one wave per row ----------------

__global__ __launch_bounds__(256) void spmm_prelu(const float* __restrict__ fts,
                                                  const int* __restrict__ row_ptr,
                                                  const int* __restrict__ col_s,
                                                  const float* __restrict__ val_s,
                                                  const float* __restrict__ b,
                                                  const float* __restrict__ a, int p, int n,
                                                  float* __restrict__ out) {
    int gid = blockIdx.x * 256 + threadIdx.x;
    int r = gid >> 6, lane = gid & 63;
    if (r >= n) return;
    int s = row_ptr[r], e = row_ptr[r + 1];
    float acc0 = 0.f, acc1 = 0.f;
    int i = s;
    for (; i + 1 < e; i += 2) {
        int c0 = col_s[i], c1 = col_s[i + 1];
        float v0 = val_s[i], v1 = val_s[i + 1];
        acc0 = fmaf(v0, fts[(size_t)c0 * 64 + lane], acc0);
        acc1 = fmaf(v1, fts[(size_t)c1 * 64 + lane], acc1);
    }
    if (i < e) acc0 = fmaf(val_s[i], fts[(size_t)col_s[i] * 64 + lane], acc0);
    float o = acc0 + acc1 + b[p * 64 + lane];
    float slope = a[p];
    out[(size_t)r * 64 + lane] = (o > 0.f) ? o : slope * o;
}

// ---------------- attention: s_sums[p][k] = sum_n tanh( embed_p[n] . fc_w[k] + fc_b[k] ) -------

__global__ __launch_bounds__(256) void fc_tanh_reduce(const float* __restrict__ embeds,
                                                      const float* __restrict__ fcw,
                                                      const float* __restrict__ fcb, int n,
                                                      float* __restrict__ s_sums) {
    __shared__ float Ws[64 * 65];
    __shared__ float Xs[4][64];
    __shared__ float red[4][64];
    int t = threadIdx.x;
    int p = blockIdx.y;
    const float* Xp = embeds + (size_t)p * n * 64;
#pragma unroll
    for (int i = 0; i < 16; i++) {
        int idx = t + i * 256;
        int k = idx >> 6, hh = idx & 63;
        Ws[hh * 65 + k] = fcw[idx];
    }
    int r = t >> 6, lane = t & 63;
    float bias = fcb[lane];
    float accsum = 0.f;
    int ngrp = (n + 3) / 4;
    for (int rg = blockIdx.x; rg < ngrp; rg += gridDim.x) {
        __syncthreads();
        int rowi = rg * 4 + r;
        Xs[r][lane] = (rowi < n) ? Xp[(size_t)rowi * 64 + lane] : 0.f;
        __syncthreads();
        float acc = bias;
#pragma unroll
        for (int hh = 0; hh < 64; hh++) acc = fmaf(Xs[r][hh], Ws[hh * 65 + lane], acc);
        if (rg * 4 + r < n) accsum += tanhf(acc);
    }
    red[r][lane] = accsum;
    __syncthreads();
    if (t < 64) {
        float v = red[0][t] + red[1][t] + red[2][t] + red[3][t];
        atomicAdd(&s_sums[p * 64 + t], v);
    }
}

__global__ __launch_bounds__(64) void compute_beta(const float* __restrict__ s_sums,
                                                   const float* __restrict__ att, int n, int P,
                                                   float* __restrict__ beta) {
    int lane = threadIdx.x;
    float av = att[lane];
    float l[8];
    for (int p = 0; p < P; p++) l[p] = s_sums[p * 64 + lane] * av;
#pragma unroll
    for (int off = 32; off > 0; off >>= 1)
        for (int p = 0; p < 8; p++)
            if (p < P) l[p] += __shfl_down(l[p], off);
    if (lane == 0) {
        const float inv = 1.0f / (float)n;
        float m = -1e30f;
        for (int p = 0; p < P; p++) {
            l[p] *= inv;
            m = fmaxf(m, l[p]);
        }
        float s = 0.f;
        for (int p = 0; p < P; p++) {
            l[p] = __expf(l[p] - m);
            s += l[p];
        }
        for (int p = 0; p < P; p++) beta[p] = l[p] / s;
    }
}

// Output is FLOAT32 (reference output dtype) — this is the round-5 experiment.
__global__ __launch_bounds__(256) void mix_out(const float* __restrict__ embeds,
                                               const float* __restrict__ beta, int n, int P,
                                               float* __restrict__ out) {
    int idx = blockIdx.x * 256 + threadIdx.x;
    size_t base = (size_t)idx * 4;
    size_t tot = (size_t)n * 64;
    if (base >= tot) return;
    float4 o = make_float4(0.f, 0.f, 0.f, 0.f);
    for (int p = 0; p < P; p++) {
        float bp = beta[p];
        float4 x = *(const float4*)(embeds + (size_t)p * tot + base);
        o.x = fmaf(bp, x.x, o.x);
        o.y = fmaf(bp, x.y, o.y);
        o.z = fmaf(bp, x.z, o.z);
        o.w = fmaf(bp, x.w, o.w);
    }
    *(float4*)(out + base) = o;
}

// ---------------- driver ----------------

extern "C" void kernel_launch(void* const* d_in, const int* in_sizes, int n_in,
                              void* d_out, int out_size, void* d_ws, size_t ws_size,
                              hipStream_t stream) {
    const float* h = (const float*)d_in[0];
    const float* W = (const float*)d_in[1];
    const float* b = (const float*)d_in[2];
    const float* a = (const float*)d_in[3];
    const float* fc_w = (const float*)d_in[4];
    const float* fc_b = (const float*)d_in[5];
    const float* att = (const float*)d_in[6];
    const float* adj = (const float*)d_in[7];
    const void* row = d_in[8];
    const void* col = d_in[9];
    const void* mask1 = d_in[10];
    const void* mask2 = d_in[11];
    float* out = (float*)d_out;

    // dynamic sizes (insurance against generated-test size changes); H fixed 64
    int P = in_sizes[3];            // a: [P]
    if (P < 1 || P > 8) P = 3;
    int N = in_sizes[0] / 64;       // h: [N,64]
    int E = in_sizes[7];            // adj_vals: [E]

    char* w = (char*)d_ws;
    auto alloc = [&](size_t bytes) {
        void* p = (void*)w;
        w += (bytes + 255) & ~(size_t)255;
        return p;
    };
    int* cnt = (int*)alloc((size_t)N * 4);
    int* row_ptr = (int*)alloc((size_t)(N + 1) * 4);
    int* cursor = (int*)alloc((size_t)N * 4);
    int* col_s = (int*)alloc((size_t)E * 4);
    float* val_s = (float*)alloc((size_t)E * 4);
    unsigned char* m1c = (unsigned char*)alloc(N);
    unsigned char* m2c = (unsigned char*)alloc(N);
    float* fts = (float*)alloc((size_t)N * 64 * 4);
    float* embeds = (float*)alloc((size_t)P * N * 64 * 4);
    float* s_sums = (float*)alloc(8 * 64 * 4);
    float* beta = (float*)alloc(8 * 4);
    int* flags = (int*)alloc(256);

    int nw_mask = N / 4 > 25000 ? 25000 : N / 4;
    int nw_idx = E / 4 > 25000 ? 25000 : E / 4;
    forensic_kernel<<<1, 256, 0, stream>>>((const unsigned int*)mask1, (const unsigned int*)row,
                                           nw_mask, nw_idx, flags);
    conv_mask_kernel<<<(N + 255) / 256, 256, 0, stream>>>(mask1, flags, N, m1c);
    conv_mask_kernel<<<(N + 255) / 256, 256, 0, stream>>>(mask2, flags, N, m2c);

    hipMemsetAsync(cnt, 0, (size_t)N * 4, stream);
    hist_kernel<<<(E + 255) / 256, 256, 0, stream>>>(row, flags, E, N, cnt);
    scan_kernel<<<1, 1024, 0, stream>>>(cnt, N, row_ptr, cursor);
    scatter_kernel<<<(E + 255) / 256, 256, 0, stream>>>(row, col, adj, flags, E, N, cursor, col_s,
                                                        val_s);

    int gemm_grid = (N + 3) / 4;
    int spmm_grid = ((size_t)N * 64 + 255) / 256;
    int mix_grid = ((size_t)N * 64 / 4 + 255) / 256;

    for (int pass = 0; pass < 3; pass++) {
        const unsigned char* msk = (pass == 0) ? m1c : (pass == 2 ? m2c : nullptr);
        // pass 2 decodes from z_mp, which lives (as f32) in d_out's first chunk
        const float* xin = (pass == 2) ? out : h;
        for (int p = 0; p < P; p++) {
            gemm64<<<gemm_grid, 256, 0, stream>>>(xin, W + p * 4096, fts, msk, N);
            spmm_prelu<<<spmm_grid, 256, 0, stream>>>(fts, row_ptr, col_s, val_s, b, a, p, N,
                                                      embeds + (size_t)p * N * 64);
        }
        hipMemsetAsync(s_sums, 0, 8 * 64 * 4, stream);
        fc_tanh_reduce<<<dim3(512, P), 256, 0, stream>>>(embeds, fc_w, fc_b, N, s_sums);
        compute_beta<<<1, 64, 0, stream>>>(s_sums, att, N, P, beta);
        mix_out<<<mix_grid, 256, 0, stream>>>(embeds, beta, N, P, out + (size_t)pass * N * 64);
    }
}

// Round 6
// 2070.577 us; speedup vs baseline: 1.1185x; 1.1185x over previous
//
#include <hip/hip_runtime.h>
#include <hip/hip_bf16.h>

typedef __hip_bfloat16 bf16;

// H is fixed at 64 by the reference architecture; N, E, P come from in_sizes.

// ---------------- dtype forensics (masks / indices) ----------------
// modes: 0=u8/bool, 1=int32, 2=float32, 3=int64, 4=float64
__global__ __launch_bounds__(256) void forensic_kernel(const unsigned int* __restrict__ mask_w,
                                                       const unsigned int* __restrict__ idx_w,
                                                       int nw_mask, int nw_idx,
                                                       int* __restrict__ flags) {
    __shared__ int sm[6];
    int t = threadIdx.x;
    if (t < 6) sm[t] = 0;
    __syncthreads();
    int m_gt1 = 0, m_f32 = 0, m_f64 = 0, m_oddnz = 0, i_hi = 0, i_oddnz = 0;
    for (int i = t; i < nw_mask; i += 256) {
        unsigned int w = mask_w[i];
        if (w > 1u && w != 0x3F800000u && w != 0x3FF00000u) m_gt1++;
        if (w == 0x3F800000u) m_f32++;
        if ((i & 1) && w == 0x3FF00000u) m_f64++;
        if ((i & 1) && w != 0u) m_oddnz++;
    }
    for (int i = t; i < nw_idx; i += 256) {
        unsigned int v = idx_w[i];
        if (v >= 0x20000000u) i_hi++;
        if ((i & 1) && v != 0u) i_oddnz++;
    }
    atomicAdd(&sm[0], m_gt1);
    atomicAdd(&sm[1], m_f32);
    atomicAdd(&sm[2], m_f64);
    atomicAdd(&sm[3], m_oddnz);
    atomicAdd(&sm[4], i_hi);
    atomicAdd(&sm[5], i_oddnz);
    __syncthreads();
    if (t == 0) {
        int mmode;
        if (sm[1] > 50) mmode = 2;
        else if (sm[2] > 50) mmode = 4;
        else if (sm[0] > 50) mmode = 0;
        else if (sm[3] > 50) mmode = 1;
        else mmode = 3;
        int imode;
        if (sm[4] > (nw_idx * 3) / 4) imode = 2;
        else if (sm[4] > nw_idx / 4) imode = 4;
        else if (sm[5] > 50) imode = 1;
        else imode = 3;
        flags[0] = mmode;
        flags[1] = imode;
    }
}

__device__ __forceinline__ int fetch_idx(const void* p, int e, int mode) {
    switch (mode) {
        case 1: return ((const int*)p)[e];
        case 3: return (int)(((const long long*)p)[e]);
        case 2: return (int)(((const float*)p)[e]);
        default: return (int)(((const double*)p)[e]);
    }
}

__global__ __launch_bounds__(256) void conv_mask_kernel(const void* __restrict__ m,
                                                        const int* __restrict__ flags, int n,
                                                        unsigned char* __restrict__ out) {
    int mode = flags[0];
    int i = blockIdx.x * 256 + threadIdx.x;
    if (i >= n) return;
    bool v;
    switch (mode) {
        case 0: v = ((const unsigned char*)m)[i] != 0; break;
        case 1: v = ((const int*)m)[i] != 0; break;
        case 2: v = ((const float*)m)[i] != 0.f; break;
        case 3: v = ((const long long*)m)[i] != 0; break;
        default: v = ((const double*)m)[i] != 0.0; break;
    }
    out[i] = v ? 1 : 0;
}

// ---------------- CSR build ----------------

__global__ __launch_bounds__(256) void hist_kernel(const void* __restrict__ row,
                                                   const int* __restrict__ flags, int e_cnt, int n,
                                                   int* __restrict__ cnt) {
    int imode = flags[1];
    int e = blockIdx.x * 256 + threadIdx.x;
    if (e >= e_cnt) return;
    int r = fetch_idx(row, e, imode);
    if ((unsigned)r < (unsigned)n) atomicAdd(&cnt[r], 1);
}

// ---- 3-stage parallel exclusive scan over cnt[0..n) (2048 elems / block) ----
// Round-6 change: replaces the single-block scan_kernel that cost ~256 µs/launch
// (uncoalesced per-thread chunk walk on one CU). All stages coalesced, grid-parallel.

__global__ __launch_bounds__(256) void scan_partial(const int* __restrict__ cnt, int n,
                                                    int* __restrict__ bsum) {
    __shared__ int red[256];
    int b = blockIdx.x, t = threadIdx.x;
    int base = b * 2048;
    int s = 0;
    for (int i = t; i < 2048; i += 256) {
        int idx = base + i;
        if (idx < n) s += cnt[idx];
    }
    red[t] = s;
    __syncthreads();
    for (int off = 128; off > 0; off >>= 1) {
        if (t < off) red[t] += red[t + off];
        __syncthreads();
    }
    if (t == 0) bsum[b] = red[0];
}

__global__ __launch_bounds__(1024) void scan_bsum(int* __restrict__ bsum, int nb,
                                                  int* __restrict__ total) {
    __shared__ int sh[1024];
    int t = threadIdx.x;
    int v = (t < nb) ? bsum[t] : 0;
    sh[t] = v;
    __syncthreads();
    for (int off = 1; off < 1024; off <<= 1) {
        int u = (t >= off) ? sh[t - off] : 0;
        __syncthreads();
        sh[t] += u;
        __syncthreads();
    }
    if (t < nb) bsum[t] = sh[t] - v;  // exclusive prefix of block sums
    if (t == 1023) *total = sh[1023];
}

__global__ __launch_bounds__(256) void scan_write(const int* __restrict__ cnt, int n,
                                                  const int* __restrict__ bsum,
                                                  const int* __restrict__ total,
                                                  int* __restrict__ row_ptr,
                                                  int* __restrict__ cursor) {
    __shared__ int red[256];
    int b = blockIdx.x, t = threadIdx.x;
    int idx0 = b * 2048 + t * 8;
    int v[8];
    int s = 0;
#pragma unroll
    for (int j = 0; j < 8; j++) {
        int idx = idx0 + j;
        v[j] = (idx < n) ? cnt[idx] : 0;
        s += v[j];
    }
    red[t] = s;
    __syncthreads();
    for (int off = 1; off < 256; off <<= 1) {
        int u = (t >= off) ? red[t - off] : 0;
        __syncthreads();
        red[t] += u;
        __syncthreads();
    }
    int run = bsum[b] + red[t] - s;  // exclusive prefix for this thread's 8 elems
#pragma unroll
    for (int j = 0; j < 8; j++) {
        int idx = idx0 + j;
        if (idx < n) {
            row_ptr[idx] = run;
            cursor[idx] = run;
            run += v[j];
        }
    }
    if (b == 0 && t == 0) row_ptr[n] = *total;
}

__global__ __launch_bounds__(256) void scatter_kernel(const void* __restrict__ row,
                                                      const void* __restrict__ col,
                                                      const float* __restrict__ vals,
                                                      const int* __restrict__ flags, int e_cnt,
                                                      int n, int* __restrict__ cursor,
                                                      int* __restrict__ col_s,
                                                      float* __restrict__ val_s) {
    int imode = flags[1];
    int e = blockIdx.x * 256 + threadIdx.x;
    if (e >= e_cnt) return;
    int r = fetch_idx(row, e, imode);
    if ((unsigned)r >= (unsigned)n) return;
    int c = fetch_idx(col, e, imode);
    if ((unsigned)c >= (unsigned)n) c = 0;
    int pos = atomicAdd(&cursor[r], 1);
    col_s[pos] = c;
    val_s[pos] = vals[e];
}

// ---------------- dense 64x64 GEMM: Y[n][k] = sum_h X[n][h] * Wg[k*64+h] ----------------
// W transposed into LDS, stride 65 (+1 pad). 4 rows / 256-thread block.

__global__ __launch_bounds__(256) void gemm64(const float* __restrict__ X,
                                              const float* __restrict__ Wg,
                                              float* __restrict__ Y,
                                              const unsigned char* __restrict__ mask, int n) {
    __shared__ float Ws[64 * 65];
    __shared__ float Xs[4][64];
    int t = threadIdx.x;
#pragma unroll
    for (int i = 0; i < 16; i++) {
        int idx = t + i * 256;
        int k = idx >> 6, hh = idx & 63;
        Ws[hh * 65 + k] = Wg[idx];
    }
    int r = t >> 6, lane = t & 63;
    int rowi = blockIdx.x * 4 + r;
    float xv = 0.f;
    if (rowi < n) {
        xv = X[(size_t)rowi * 64 + lane];
        if (mask != nullptr && mask[rowi]) xv = 0.f;
    }
    Xs[r][lane] = xv;
    __syncthreads();
    float acc = 0.f;
#pragma unroll
    for (int hh = 0; hh < 64; hh++) acc = fmaf(Xs[r][hh], Ws[hh * 65 + lane], acc);
    if (rowi < n) Y[(size_t)rowi * 64 + lane] = acc;
}

// ---------------- CSR SpMM + bias + PReLU: one wave per row ----------------

__global__ __launch_bounds__(256) void spmm_prelu(const float* __restrict__ fts,
                                                  const int* __restrict__ row_ptr,
                                                  const int* __restrict__ col_s,
                                                  const float* __restrict__ val_s,
                                                  const float* __restrict__ b,
                                                  const float* __restrict__ a, int p, int n,
                                                  float* __restrict__ out) {
    int gid = blockIdx.x * 256 + threadIdx.x;
    int r = gid >> 6, lane = gid & 63;
    if (r >= n) return;
    int s = row_ptr[r], e = row_ptr[r + 1];
    float acc0 = 0.f, acc1 = 0.f;
    int i = s;
    for (; i + 1 < e; i += 2) {
        int c0 = col_s[i], c1 = col_s[i + 1];
        float v0 = val_s[i], v1 = val_s[i + 1];
        acc0 = fmaf(v0, fts[(size_t)c0 * 64 + lane], acc0);
        acc1 = fmaf(v1, fts[(size_t)c1 * 64 + lane], acc1);
    }
    if (i < e) acc0 = fmaf(val_s[i], fts[(size_t)col_s[i] * 64 + lane], acc0);
    float o = acc0 + acc1 + b[p * 64 + lane];
    float slope = a[p];
    out[(size_t)r * 64 + lane] = (o > 0.f) ? o : slope * o;
}

// ---------------- attention: s_sums[p][k] = sum_n tanh( embed_p[n] . fc_w[k] + fc_b[k] ) -------

__global__ __launch_bounds__(256) void fc_tanh_reduce(const float* __restrict__ embeds,
                                                      const float* __restrict__ fcw,
                                                      const float* __restrict__ fcb, int n,
                                                      float* __restrict__ s_sums) {
    __shared__ float Ws[64 * 65];
    __shared__ float Xs[4][64];
    __shared__ float red[4][64];
    int t = threadIdx.x;
    int p = blockIdx.y;
    const float* Xp = embeds + (size_t)p * n * 64;
#pragma unroll
    for (int i = 0; i < 16; i++) {
        int idx = t + i * 256;
        int k = idx >> 6, hh = idx & 63;
        Ws[hh * 65 + k] = fcw[idx];
    }
    int r = t >> 6, lane = t & 63;
    float bias = fcb[lane];
    float accsum = 0.f;
    int ngrp = (n + 3) / 4;
    for (int rg = blockIdx.x; rg < ngrp; rg += gridDim.x) {
        __syncthreads();
        int rowi = rg * 4 + r;
        Xs[r][lane] = (rowi < n) ? Xp[(size_t)rowi * 64 + lane] : 0.f;
        __syncthreads();
        float acc = bias;
#pragma unroll
        for (int hh = 0; hh < 64; hh++) acc = fmaf(Xs[r][hh], Ws[hh * 65 + lane], acc);
        if (rg * 4 + r < n) accsum += tanhf(acc);
    }
    red[r][lane] = accsum;
    __syncthreads();
    if (t < 64) {
        float v = red[0][t] + red[1][t] + red[2][t] + red[3][t];
        atomicAdd(&s_sums[p * 64 + t], v);
    }
}

__global__ __launch_bounds__(64) void compute_beta(const float* __restrict__ s_sums,
                                                   const float* __restrict__ att, int n, int P,
                                                   float* __restrict__ beta) {
    int lane = threadIdx.x;
    float av = att[lane];
    float l[8];
    for (int p = 0; p < P; p++) l[p] = s_sums[p * 64 + lane] * av;
#pragma unroll
    for (int off = 32; off > 0; off >>= 1)
        for (int p = 0; p < 8; p++)
            if (p < P) l[p] += __shfl_down(l[p], off);
    if (lane == 0) {
        const float inv = 1.0f / (float)n;
        float m = -1e30f;
        for (int p = 0; p < P; p++) {
            l[p] *= inv;
            m = fmaxf(m, l[p]);
        }
        float s = 0.f;
        for (int p = 0; p < P; p++) {
            l[p] = __expf(l[p] - m);
            s += l[p];
        }
        for (int p = 0; p < P; p++) beta[p] = l[p] / s;
    }
}

// Output dtype is FLOAT32 (verified round 5).
__global__ __launch_bounds__(256) void mix_out(const float* __restrict__ embeds,
                                               const float* __restrict__ beta, int n, int P,
                                               float* __restrict__ out) {
    int idx = blockIdx.x * 256 + threadIdx.x;
    size_t base = (size_t)idx * 4;
    size_t tot = (size_t)n * 64;
    if (base >= tot) return;
    float4 o = make_float4(0.f, 0.f, 0.f, 0.f);
    for (int p = 0; p < P; p++) {
        float bp = beta[p];
        float4 x = *(const float4*)(embeds + (size_t)p * tot + base);
        o.x = fmaf(bp, x.x, o.x);
        o.y = fmaf(bp, x.y, o.y);
        o.z = fmaf(bp, x.z, o.z);
        o.w = fmaf(bp, x.w, o.w);
    }
    *(float4*)(out + base) = o;
}

// ---------------- driver ----------------

extern "C" void kernel_launch(void* const* d_in, const int* in_sizes, int n_in,
                              void* d_out, int out_size, void* d_ws, size_t ws_size,
                              hipStream_t stream) {
    const float* h = (const float*)d_in[0];
    const float* W = (const float*)d_in[1];
    const float* b = (const float*)d_in[2];
    const float* a = (const float*)d_in[3];
    const float* fc_w = (const float*)d_in[4];
    const float* fc_b = (const float*)d_in[5];
    const float* att = (const float*)d_in[6];
    const float* adj = (const float*)d_in[7];
    const void* row = d_in[8];
    const void* col = d_in[9];
    const void* mask1 = d_in[10];
    const void* mask2 = d_in[11];
    float* out = (float*)d_out;

    int P = in_sizes[3];       // a: [P]
    if (P < 1 || P > 8) P = 3;
    int N = in_sizes[0] / 64;  // h: [N,64]
    int E = in_sizes[7];       // adj_vals: [E]

    char* w = (char*)d_ws;
    auto alloc = [&](size_t bytes) {
        void* p = (void*)w;
        w += (bytes + 255) & ~(size_t)255;
        return p;
    };
    int* cnt = (int*)alloc((size_t)N * 4);
    int* row_ptr = (int*)alloc((size_t)(N + 1) * 4);
    int* cursor = (int*)alloc((size_t)N * 4);
    int* col_s = (int*)alloc((size_t)E * 4);
    float* val_s = (float*)alloc((size_t)E * 4);
    unsigned char* m1c = (unsigned char*)alloc(N);
    unsigned char* m2c = (unsigned char*)alloc(N);
    float* fts = (float*)alloc((size_t)N * 64 * 4);
    float* embeds = (float*)alloc((size_t)P * N * 64 * 4);
    float* s_sums = (float*)alloc(8 * 64 * 4);
    float* beta = (float*)alloc(8 * 4);
    int* flags = (int*)alloc(256);
    int nsb = (N + 2047) / 2048;
    int* bsum = (int*)alloc((size_t)(nsb + 1) * 4);
    int* etotal = (int*)alloc(256);

    int nw_mask = N / 4 > 25000 ? 25000 : N / 4;
    int nw_idx = E / 4 > 25000 ? 25000 : E / 4;
    forensic_kernel<<<1, 256, 0, stream>>>((const unsigned int*)mask1, (const unsigned int*)row,
                                           nw_mask, nw_idx, flags);
    conv_mask_kernel<<<(N + 255) / 256, 256, 0, stream>>>(mask1, flags, N, m1c);
    conv_mask_kernel<<<(N + 255) / 256, 256, 0, stream>>>(mask2, flags, N, m2c);

    hipMemsetAsync(cnt, 0, (size_t)N * 4, stream);
    hist_kernel<<<(E + 255) / 256, 256, 0, stream>>>(row, flags, E, N, cnt);
    scan_partial<<<nsb, 256, 0, stream>>>(cnt, N, bsum);
    scan_bsum<<<1, 1024, 0, stream>>>(bsum, nsb, etotal);
    scan_write<<<nsb, 256, 0, stream>>>(cnt, N, bsum, etotal, row_ptr, cursor);
    scatter_kernel<<<(E + 255) / 256, 256, 0, stream>>>(row, col, adj, flags, E, N, cursor, col_s,
                                                        val_s);

    int gemm_grid = (N + 3) / 4;
    int spmm_grid = ((size_t)N * 64 + 255) / 256;
    int mix_grid = ((size_t)N * 64 / 4 + 255) / 256;

    for (int pass = 0; pass < 3; pass++) {
        const unsigned char* msk = (pass == 0) ? m1c : (pass == 2 ? m2c : nullptr);
        // pass 2 decodes from z_mp, which lives (as f32) in d_out's first chunk
        const float* xin = (pass == 2) ? out : h;
        for (int p = 0; p < P; p++) {
            gemm64<<<gemm_grid, 256, 0, stream>>>(xin, W + p * 4096, fts, msk, N);
            spmm_prelu<<<spmm_grid, 256, 0, stream>>>(fts, row_ptr, col_s, val_s, b, a, p, N,
                                                      embeds + (size_t)p * N * 64);
        }
        hipMemsetAsync(s_sums, 0, 8 * 64 * 4, stream);
        fc_tanh_reduce<<<dim3(512, P), 256, 0, stream>>>(embeds, fc_w, fc_b, N, s_sums);
        compute_beta<<<1, 64, 0, stream>>>(s_sums, att, N, P, beta);
        mix_out<<<mix_grid, 256, 0, stream>>>(embeds, beta, N, P, out + (size_t)pass * N * 64);
    }
}

// Round 7
// 1500.463 us; speedup vs baseline: 1.5435x; 1.3800x over previous
//
#include <hip/hip_runtime.h>
#include <hip/hip_bf16.h>

typedef __hip_bfloat16 bf16;
typedef __attribute__((ext_vector_type(8))) short bf16x8;  // 8 bf16 in 4 VGPRs
typedef __attribute__((ext_vector_type(4))) float f32x4;

// ---------------- bf16 split helpers (Ootomo bf16x3 scheme) ----------------

__device__ __forceinline__ short f2bf(float x) {  // RNE float->bf16 bits
    unsigned u = __float_as_uint(x);
    unsigned r = (u + 0x7FFFu + ((u >> 16) & 1u)) >> 16;
    return (short)r;
}
__device__ __forceinline__ float bf2f(short s) {
    return __uint_as_float(((unsigned)(unsigned short)s) << 16);
}

// Load 8 consecutive floats (16B-aligned), split into hi/lo bf16 fragments.
__device__ __forceinline__ void split8(const float* __restrict__ p, bool ok, bf16x8& hi,
                                       bf16x8& lo) {
    float v[8];
    if (ok) {
        float4 x0 = ((const float4*)p)[0];
        float4 x1 = ((const float4*)p)[1];
        v[0] = x0.x; v[1] = x0.y; v[2] = x0.z; v[3] = x0.w;
        v[4] = x1.x; v[5] = x1.y; v[6] = x1.z; v[7] = x1.w;
    } else {
#pragma unroll
        for (int j = 0; j < 8; j++) v[j] = 0.f;
    }
#pragma unroll
    for (int j = 0; j < 8; j++) {
        short hb = f2bf(v[j]);
        hi[j] = hb;
        lo[j] = f2bf(v[j] - bf2f(hb));
    }
}

// ---------------- dtype forensics (masks / indices) ----------------
// modes: 0=u8/bool, 1=int32, 2=float32, 3=int64, 4=float64
__global__ __launch_bounds__(256) void forensic_kernel(const unsigned int* __restrict__ mask_w,
                                                       const unsigned int* __restrict__ idx_w,
                                                       int nw_mask, int nw_idx,
                                                       int* __restrict__ flags) {
    __shared__ int sm[6];
    int t = threadIdx.x;
    if (t < 6) sm[t] = 0;
    __syncthreads();
    int m_gt1 = 0, m_f32 = 0, m_f64 = 0, m_oddnz = 0, i_hi = 0, i_oddnz = 0;
    for (int i = t; i < nw_mask; i += 256) {
        unsigned int w = mask_w[i];
        if (w > 1u && w != 0x3F800000u && w != 0x3FF00000u) m_gt1++;
        if (w == 0x3F800000u) m_f32++;
        if ((i & 1) && w == 0x3FF00000u) m_f64++;
        if ((i & 1) && w != 0u) m_oddnz++;
    }
    for (int i = t; i < nw_idx; i += 256) {
        unsigned int v = idx_w[i];
        if (v >= 0x20000000u) i_hi++;
        if ((i & 1) && v != 0u) i_oddnz++;
    }
    atomicAdd(&sm[0], m_gt1);
    atomicAdd(&sm[1], m_f32);
    atomicAdd(&sm[2], m_f64);
    atomicAdd(&sm[3], m_oddnz);
    atomicAdd(&sm[4], i_hi);
    atomicAdd(&sm[5], i_oddnz);
    __syncthreads();
    if (t == 0) {
        int mmode;
        if (sm[1] > 50) mmode = 2;
        else if (sm[2] > 50) mmode = 4;
        else if (sm[0] > 50) mmode = 0;
        else if (sm[3] > 50) mmode = 1;
        else mmode = 3;
        int imode;
        if (sm[4] > (nw_idx * 3) / 4) imode = 2;
        else if (sm[4] > nw_idx / 4) imode = 4;
        else if (sm[5] > 50) imode = 1;
        else imode = 3;
        flags[0] = mmode;
        flags[1] = imode;
    }
}

__device__ __forceinline__ int fetch_idx(const void* p, int e, int mode) {
    switch (mode) {
        case 1: return ((const int*)p)[e];
        case 3: return (int)(((const long long*)p)[e]);
        case 2: return (int)(((const float*)p)[e]);
        default: return (int)(((const double*)p)[e]);
    }
}

__global__ __launch_bounds__(256) void conv_mask_kernel(const void* __restrict__ m,
                                                        const int* __restrict__ flags, int n,
                                                        unsigned char* __restrict__ out) {
    int mode = flags[0];
    int i = blockIdx.x * 256 + threadIdx.x;
    if (i >= n) return;
    bool v;
    switch (mode) {
        case 0: v = ((const unsigned char*)m)[i] != 0; break;
        case 1: v = ((const int*)m)[i] != 0; break;
        case 2: v = ((const float*)m)[i] != 0.f; break;
        case 3: v = ((const long long*)m)[i] != 0; break;
        default: v = ((const double*)m)[i] != 0.0; break;
    }
    out[i] = v ? 1 : 0;
}

// ---------------- CSR build ----------------

__global__ __launch_bounds__(256) void hist_kernel(const void* __restrict__ row,
                                                   const int* __restrict__ flags, int e_cnt, int n,
                                                   int* __restrict__ cnt) {
    int imode = flags[1];
    int e = blockIdx.x * 256 + threadIdx.x;
    if (e >= e_cnt) return;
    int r = fetch_idx(row, e, imode);
    if ((unsigned)r < (unsigned)n) atomicAdd(&cnt[r], 1);
}

__global__ __launch_bounds__(256) void scan_partial(const int* __restrict__ cnt, int n,
                                                    int* __restrict__ bsum) {
    __shared__ int red[256];
    int b = blockIdx.x, t = threadIdx.x;
    int base = b * 2048;
    int s = 0;
    for (int i = t; i < 2048; i += 256) {
        int idx = base + i;
        if (idx < n) s += cnt[idx];
    }
    red[t] = s;
    __syncthreads();
    for (int off = 128; off > 0; off >>= 1) {
        if (t < off) red[t] += red[t + off];
        __syncthreads();
    }
    if (t == 0) bsum[b] = red[0];
}

__global__ __launch_bounds__(1024) void scan_bsum(int* __restrict__ bsum, int nb,
                                                  int* __restrict__ total) {
    __shared__ int sh[1024];
    int t = threadIdx.x;
    int v = (t < nb) ? bsum[t] : 0;
    sh[t] = v;
    __syncthreads();
    for (int off = 1; off < 1024; off <<= 1) {
        int u = (t >= off) ? sh[t - off] : 0;
        __syncthreads();
        sh[t] += u;
        __syncthreads();
    }
    if (t < nb) bsum[t] = sh[t] - v;
    if (t == 1023) *total = sh[1023];
}

__global__ __launch_bounds__(256) void scan_write(const int* __restrict__ cnt, int n,
                                                  const int* __restrict__ bsum,
                                                  const int* __restrict__ total,
                                                  int* __restrict__ row_ptr,
                                                  int* __restrict__ cursor) {
    __shared__ int red[256];
    int b = blockIdx.x, t = threadIdx.x;
    int idx0 = b * 2048 + t * 8;
    int v[8];
    int s = 0;
#pragma unroll
    for (int j = 0; j < 8; j++) {
        int idx = idx0 + j;
        v[j] = (idx < n) ? cnt[idx] : 0;
        s += v[j];
    }
    red[t] = s;
    __syncthreads();
    for (int off = 1; off < 256; off <<= 1) {
        int u = (t >= off) ? red[t - off] : 0;
        __syncthreads();
        red[t] += u;
        __syncthreads();
    }
    int run = bsum[b] + red[t] - s;
#pragma unroll
    for (int j = 0; j < 8; j++) {
        int idx = idx0 + j;
        if (idx < n) {
            row_ptr[idx] = run;
            cursor[idx] = run;
            run += v[j];
        }
    }
    if (b == 0 && t == 0) row_ptr[n] = *total;
}

__global__ __launch_bounds__(256) void scatter_kernel(const void* __restrict__ row,
                                                      const void* __restrict__ col,
                                                      const float* __restrict__ vals,
                                                      const int* __restrict__ flags, int e_cnt,
                                                      int n, int* __restrict__ cursor,
                                                      int* __restrict__ col_s,
                                                      float* __restrict__ val_s) {
    int imode = flags[1];
    int e = blockIdx.x * 256 + threadIdx.x;
    if (e >= e_cnt) return;
    int r = fetch_idx(row, e, imode);
    if ((unsigned)r >= (unsigned)n) return;
    int c = fetch_idx(col, e, imode);
    if ((unsigned)c >= (unsigned)n) c = 0;
    int pos = atomicAdd(&cursor[r], 1);
    col_s[pos] = c;
    val_s[pos] = vals[e];
}

// ---------------- MFMA dense GEMM: Y[p][r][c] = sum_h X[r][h] * Wg[p][c][h] ----------------
// 16x16x32 bf16 MFMA, bf16x3 split for ~f32 precision. Wave wv owns col-tile
// [wv*16, wv*16+16); W fragments preloaded in registers, reused across all row
// tiles (grid-stride). A layout: A[m=lane&15][k=(lane>>4)*8+j]; B mirrored;
// C/D: col=lane&15, row=(lane>>4)*4+reg  [measured m89/m91/m120].

template <int PP>
__global__ __launch_bounds__(256) void gemm_mfma(const float* __restrict__ X,
                                                 const float* __restrict__ Wg,
                                                 float* __restrict__ Y,
                                                 const unsigned char* __restrict__ mask, int n) {
    int t = threadIdx.x;
    int wv = t >> 6, lane = t & 63, nl = lane & 15, q = lane >> 4;
    int colg = wv * 16 + nl;
    bf16x8 bhi[PP][2], blo[PP][2];
#pragma unroll
    for (int p = 0; p < PP; p++)
#pragma unroll
        for (int kk = 0; kk < 2; kk++)
            split8(Wg + p * 4096 + colg * 64 + kk * 32 + q * 8, true, bhi[p][kk], blo[p][kk]);
    int ntiles = (n + 15) >> 4;
    for (int rt = blockIdx.x; rt < ntiles; rt += gridDim.x) {
        int rowi = rt * 16 + nl;
        bool ok = (rowi < n) && !(mask != nullptr && mask[rowi]);
        bf16x8 ah[2], al[2];
#pragma unroll
        for (int kk = 0; kk < 2; kk++)
            split8(X + (size_t)rowi * 64 + kk * 32 + q * 8, ok, ah[kk], al[kk]);
#pragma unroll
        for (int p = 0; p < PP; p++) {
            f32x4 acc = {0.f, 0.f, 0.f, 0.f};
            acc = __builtin_amdgcn_mfma_f32_16x16x32_bf16(ah[0], bhi[p][0], acc, 0, 0, 0);
            acc = __builtin_amdgcn_mfma_f32_16x16x32_bf16(ah[1], bhi[p][1], acc, 0, 0, 0);
            acc = __builtin_amdgcn_mfma_f32_16x16x32_bf16(al[0], bhi[p][0], acc, 0, 0, 0);
            acc = __builtin_amdgcn_mfma_f32_16x16x32_bf16(al[1], bhi[p][1], acc, 0, 0, 0);
            acc = __builtin_amdgcn_mfma_f32_16x16x32_bf16(ah[0], blo[p][0], acc, 0, 0, 0);
            acc = __builtin_amdgcn_mfma_f32_16x16x32_bf16(ah[1], blo[p][1], acc, 0, 0, 0);
#pragma unroll
            for (int i = 0; i < 4; i++) {
                int r = rt * 16 + q * 4 + i;
                if (r < n) Y[(size_t)p * n * 64 + (size_t)r * 64 + colg] = acc[i];
            }
        }
    }
}

// ---------------- CSR SpMM + bias + PReLU, all P layers (blockIdx.y = p) ----------------

__global__ __launch_bounds__(256) void spmm_all(const float* __restrict__ fts,
                                                const int* __restrict__ row_ptr,
                                                const int* __restrict__ col_s,
                                                const float* __restrict__ val_s,
                                                const float* __restrict__ b,
                                                const float* __restrict__ a, int n,
                                                float* __restrict__ embeds) {
    int p = blockIdx.y;
    const float* F = fts + (size_t)p * n * 64;
    float* O = embeds + (size_t)p * n * 64;
    int gid = blockIdx.x * 256 + threadIdx.x;
    int r = gid >> 6, lane = gid & 63;
    if (r >= n) return;
    int s = row_ptr[r], e = row_ptr[r + 1];
    float acc0 = 0.f, acc1 = 0.f;
    int i = s;
    for (; i + 1 < e; i += 2) {
        int c0 = col_s[i], c1 = col_s[i + 1];
        float v0 = val_s[i], v1 = val_s[i + 1];
        acc0 = fmaf(v0, F[(size_t)c0 * 64 + lane], acc0);
        acc1 = fmaf(v1, F[(size_t)c1 * 64 + lane], acc1);
    }
    if (i < e) acc0 = fmaf(val_s[i], F[(size_t)col_s[i] * 64 + lane], acc0);
    float o = acc0 + acc1 + b[p * 64 + lane];
    float slope = a[p];
    O[(size_t)r * 64 + lane] = (o > 0.f) ? o : slope * o;
}

// ---------------- attention: s_sums[p][k] = sum_n tanh( embed_p[n] . fc_w[k] + fc_b[k] ) ------
// Same MFMA core; tanh applied on C fragments, column sums reduced cross-lane.

__global__ __launch_bounds__(256) void fc_tanh_mfma(const float* __restrict__ embeds,
                                                    const float* __restrict__ fcw,
                                                    const float* __restrict__ fcb, int n,
                                                    float* __restrict__ s_sums) {
    int p = blockIdx.y;
    const float* X = embeds + (size_t)p * n * 64;
    int t = threadIdx.x;
    int wv = t >> 6, lane = t & 63, nl = lane & 15, q = lane >> 4;
    int colg = wv * 16 + nl;
    bf16x8 bhi[2], blo[2];
#pragma unroll
    for (int kk = 0; kk < 2; kk++)
        split8(fcw + colg * 64 + kk * 32 + q * 8, true, bhi[kk], blo[kk]);
    float bias = fcb[colg];
    float ssum = 0.f;
    int ntiles = (n + 15) >> 4;
    for (int rt = blockIdx.x; rt < ntiles; rt += gridDim.x) {
        int rowi = rt * 16 + nl;
        bool ok = rowi < n;
        bf16x8 ah[2], al[2];
#pragma unroll
        for (int kk = 0; kk < 2; kk++)
            split8(X + (size_t)rowi * 64 + kk * 32 + q * 8, ok, ah[kk], al[kk]);
        f32x4 acc = {0.f, 0.f, 0.f, 0.f};
        acc = __builtin_amdgcn_mfma_f32_16x16x32_bf16(ah[0], bhi[0], acc, 0, 0, 0);
        acc = __builtin_amdgcn_mfma_f32_16x16x32_bf16(ah[1], bhi[1], acc, 0, 0, 0);
        acc = __builtin_amdgcn_mfma_f32_16x16x32_bf16(al[0], bhi[0], acc, 0, 0, 0);
        acc = __builtin_amdgcn_mfma_f32_16x16x32_bf16(al[1], bhi[1], acc, 0, 0, 0);
        acc = __builtin_amdgcn_mfma_f32_16x16x32_bf16(ah[0], blo[0], acc, 0, 0, 0);
        acc = __builtin_amdgcn_mfma_f32_16x16x32_bf16(ah[1], blo[1], acc, 0, 0, 0);
#pragma unroll
        for (int i = 0; i < 4; i++) {
            int r = rt * 16 + q * 4 + i;
            if (r < n) ssum += tanhf(acc[i] + bias);
        }
    }
    ssum += __shfl_xor(ssum, 16);
    ssum += __shfl_xor(ssum, 32);
    if (q == 0) atomicAdd(&s_sums[p * 64 + colg], ssum);
}

__global__ __launch_bounds__(64) void compute_beta(const float* __restrict__ s_sums,
                                                   const float* __restrict__ att, int n, int P,
                                                   float* __restrict__ beta) {
    int lane = threadIdx.x;
    float av = att[lane];
    float l[8];
    for (int p = 0; p < P; p++) l[p] = s_sums[p * 64 + lane] * av;
#pragma unroll
    for (int off = 32; off > 0; off >>= 1)
        for (int p = 0; p < 8; p++)
            if (p < P) l[p] += __shfl_down(l[p], off);
    if (lane == 0) {
        const float inv = 1.0f / (float)n;
        float m = -1e30f;
        for (int p = 0; p < P; p++) {
            l[p] *= inv;
            m = fmaxf(m, l[p]);
        }
        float s = 0.f;
        for (int p = 0; p < P; p++) {
            l[p] = __expf(l[p] - m);
            s += l[p];
        }
        for (int p = 0; p < P; p++) beta[p] = l[p] / s;
    }
}

// Output dtype FLOAT32 (verified round 5).
__global__ __launch_bounds__(256) void mix_out(const float* __restrict__ embeds,
                                               const float* __restrict__ beta, int n, int P,
                                               float* __restrict__ out) {
    int idx = blockIdx.x * 256 + threadIdx.x;
    size_t base = (size_t)idx * 4;
    size_t tot = (size_t)n * 64;
    if (base >= tot) return;
    float4 o = make_float4(0.f, 0.f, 0.f, 0.f);
    for (int p = 0; p < P; p++) {
        float bp = beta[p];
        float4 x = *(const float4*)(embeds + (size_t)p * tot + base);
        o.x = fmaf(bp, x.x, o.x);
        o.y = fmaf(bp, x.y, o.y);
        o.z = fmaf(bp, x.z, o.z);
        o.w = fmaf(bp, x.w, o.w);
    }
    *(float4*)(out + base) = o;
}

// ---------------- driver ----------------

extern "C" void kernel_launch(void* const* d_in, const int* in_sizes, int n_in,
                              void* d_out, int out_size, void* d_ws, size_t ws_size,
                              hipStream_t stream) {
    const float* h = (const float*)d_in[0];
    const float* W = (const float*)d_in[1];
    const float* b = (const float*)d_in[2];
    const float* a = (const float*)d_in[3];
    const float* fc_w = (const float*)d_in[4];
    const float* fc_b = (const float*)d_in[5];
    const float* att = (const float*)d_in[6];
    const float* adj = (const float*)d_in[7];
    const void* row = d_in[8];
    const void* col = d_in[9];
    const void* mask1 = d_in[10];
    const void* mask2 = d_in[11];
    float* out = (float*)d_out;

    int P = in_sizes[3];
    if (P < 1 || P > 8) P = 3;
    int N = in_sizes[0] / 64;
    int E = in_sizes[7];

    char* w = (char*)d_ws;
    auto alloc = [&](size_t bytes) {
        void* p = (void*)w;
        w += (bytes + 255) & ~(size_t)255;
        return p;
    };
    int* cnt = (int*)alloc((size_t)N * 4);
    int* row_ptr = (int*)alloc((size_t)(N + 1) * 4);
    int* cursor = (int*)alloc((size_t)N * 4);
    int* col_s = (int*)alloc((size_t)E * 4);
    float* val_s = (float*)alloc((size_t)E * 4);
    unsigned char* m1c = (unsigned char*)alloc(N);
    unsigned char* m2c = (unsigned char*)alloc(N);
    float* fts = (float*)alloc((size_t)P * N * 64 * 4);
    float* embeds = (float*)alloc((size_t)P * N * 64 * 4);
    float* s_sums = (float*)alloc(8 * 64 * 4);
    float* beta = (float*)alloc(8 * 4);
    int* flags = (int*)alloc(256);
    int nsb = (N + 2047) / 2048;
    int* bsum = (int*)alloc((size_t)(nsb + 1) * 4);
    int* etotal = (int*)alloc(256);

    int nw_mask = N / 4 > 25000 ? 25000 : N / 4;
    int nw_idx = E / 4 > 25000 ? 25000 : E / 4;
    forensic_kernel<<<1, 256, 0, stream>>>((const unsigned int*)mask1, (const unsigned int*)row,
                                           nw_mask, nw_idx, flags);
    conv_mask_kernel<<<(N + 255) / 256, 256, 0, stream>>>(mask1, flags, N, m1c);
    conv_mask_kernel<<<(N + 255) / 256, 256, 0, stream>>>(mask2, flags, N, m2c);

    hipMemsetAsync(cnt, 0, (size_t)N * 4, stream);
    hist_kernel<<<(E + 255) / 256, 256, 0, stream>>>(row, flags, E, N, cnt);
    scan_partial<<<nsb, 256, 0, stream>>>(cnt, N, bsum);
    scan_bsum<<<1, 1024, 0, stream>>>(bsum, nsb, etotal);
    scan_write<<<nsb, 256, 0, stream>>>(cnt, N, bsum, etotal, row_ptr, cursor);
    scatter_kernel<<<(E + 255) / 256, 256, 0, stream>>>(row, col, adj, flags, E, N, cursor, col_s,
                                                        val_s);

    int spmm_grid = ((size_t)N * 64 + 255) / 256;
    int mix_grid = ((size_t)N * 64 / 4 + 255) / 256;
    int gemm_blocks = 1024;
    int fc_blocks = 512;

    for (int pass = 0; pass < 3; pass++) {
        const unsigned char* msk = (pass == 0) ? m1c : (pass == 2 ? m2c : nullptr);
        const float* xin = (pass == 2) ? out : h;  // pass 2 decodes from z_mp (f32, in d_out)
        if (P == 3) {
            gemm_mfma<3><<<gemm_blocks, 256, 0, stream>>>(xin, W, fts, msk, N);
        } else {
            for (int p = 0; p < P; p++)
                gemm_mfma<1><<<gemm_blocks, 256, 0, stream>>>(xin, W + p * 4096,
                                                              fts + (size_t)p * N * 64, msk, N);
        }
        spmm_all<<<dim3(spmm_grid, P), 256, 0, stream>>>(fts, row_ptr, col_s, val_s, b, a, N,
                                                         embeds);
        hipMemsetAsync(s_sums, 0, 8 * 64 * 4, stream);
        fc_tanh_mfma<<<dim3(fc_blocks, P), 256, 0, stream>>>(embeds, fc_w, fc_b, N, s_sums);
        compute_beta<<<1, 64, 0, stream>>>(s_sums, att, N, P, beta);
        mix_out<<<mix_grid, 256, 0, stream>>>(embeds, beta, N, P, out + (size_t)pass * N * 64);
    }
}